// Round 16
// baseline (865.834 us; speedup 1.0000x reference)
//
#include <hip/hip_runtime.h>
#include <hip/hip_bf16.h>

using bf16 = __hip_bfloat16;
typedef __attribute__((ext_vector_type(8))) short short8;
typedef __attribute__((ext_vector_type(4))) float f32x4;

__device__ __forceinline__ unsigned short f2bu(float x) {
  union { bf16 b; unsigned short u; } cv; cv.b = __float2bfloat16(x); return cv.u;
}

__device__ __forceinline__ void gload_lds16(const bf16* g, bf16* l) {
  __builtin_amdgcn_global_load_lds(
      (const __attribute__((address_space(1))) void*)g,
      (__attribute__((address_space(3))) void*)l, 16, 0, 0);
}

// ---- merged transpose + fp32->bf16 (4 weight tensors in one launch) ---------
__global__ __launch_bounds__(256) void transpose4(
    const float* __restrict__ i0, bf16* __restrict__ o0,
    const float* __restrict__ i1, bf16* __restrict__ o1,
    const float* __restrict__ i2, bf16* __restrict__ o2,
    const float* __restrict__ i3, bf16* __restrict__ o3) {
  __shared__ float tile[64][65];
  int bid = blockIdx.x;
  const float* in; bf16* out; int R, C, bx, by, bz = 0;
  if (bid < 768)        { in = i0; out = o0; R = 1024; C = 3072; bx = bid % 48; by = bid / 48; }
  else if (bid < 1024)  { int b = bid - 768;  in = i1; out = o1; R = 1024; C = 1024; bx = b % 16; by = b / 16; }
  else if (bid < 5120)  { int b = bid - 1024; in = i2; out = o2; R = 1024; C = 2048; bz = b >> 9; int lb = b & 511; bx = lb % 32; by = lb / 32; }
  else                  { int b = bid - 5120; in = i3; out = o3; R = 2048; C = 1024; bz = b >> 9; int lb = b & 511; bx = lb % 16; by = lb / 16; }
  size_t bo = (size_t)bz * R * C;
  in += bo; out += bo;
  int c0 = bx * 64, r0 = by * 64;
  int tx = threadIdx.x & 15, ty = threadIdx.x >> 4;  // 16 x 16
#pragma unroll
  for (int i = 0; i < 4; ++i) {
    float4 v = *(const float4*)&in[(size_t)(r0 + ty + i * 16) * C + c0 + tx * 4];
    tile[ty + i * 16][tx * 4 + 0] = v.x;
    tile[ty + i * 16][tx * 4 + 1] = v.y;
    tile[ty + i * 16][tx * 4 + 2] = v.z;
    tile[ty + i * 16][tx * 4 + 3] = v.w;
  }
  __syncthreads();
  int rr0 = (threadIdx.x & 15) * 4;
  int cg = threadIdx.x >> 4;
#pragma unroll
  for (int jj = 0; jj < 4; ++jj) {
    int cc = jj * 16 + cg;
    ushort4 o;
    o.x = f2bu(tile[rr0 + 0][cc]);
    o.y = f2bu(tile[rr0 + 1][cc]);
    o.z = f2bu(tile[rr0 + 2][cc]);
    o.w = f2bu(tile[rr0 + 3][cc]);
    *(ushort4*)&out[(size_t)(c0 + cc) * R + r0 + rr0] = o;
  }
}

// ---------------- LayerNorm: fp32 in -> bf16 out (row = 1024) ----------------
__global__ __launch_bounds__(256) void ln_kernel(
    const float* __restrict__ in, const float* __restrict__ sc,
    const float* __restrict__ bi, bf16* __restrict__ out) {
  int row = blockIdx.x, tid = threadIdx.x;
  const float4* xr = (const float4*)(in + (size_t)row * 1024);
  float4 v = xr[tid];
  float s = v.x + v.y + v.z + v.w;
  float sq = v.x * v.x + v.y * v.y + v.z * v.z + v.w * v.w;
#pragma unroll
  for (int m = 1; m < 64; m <<= 1) { s += __shfl_xor(s, m); sq += __shfl_xor(sq, m); }
  __shared__ float red[8];
  int wid = tid >> 6, lane = tid & 63;
  if (lane == 0) { red[wid] = s; red[4 + wid] = sq; }
  __syncthreads();
  s = red[0] + red[1] + red[2] + red[3];
  sq = red[4] + red[5] + red[6] + red[7];
  float mu = s * (1.f / 1024.f);
  float rstd = rsqrtf(sq * (1.f / 1024.f) - mu * mu + 1e-6f);
  float4 scv = ((const float4*)sc)[tid];
  float4 biv = ((const float4*)bi)[tid];
  ushort4 ov;
  ov.x = f2bu((v.x - mu) * rstd * scv.x + biv.x);
  ov.y = f2bu((v.y - mu) * rstd * scv.y + biv.y);
  ov.z = f2bu((v.z - mu) * rstd * scv.z + biv.z);
  ov.w = f2bu((v.w - mu) * rstd * scv.w + biv.w);
  ((ushort4*)(out + (size_t)row * 1024))[tid] = ov;
}

// ---- GEMM: single-buffer m97-structure + T1 XCD swizzle ---------------------
// grid.x*grid.y must be %8==0 (all launch configs satisfy this).
template <int BM, int BN, int EPI, bool GATHER, bool GROUPED>
__global__ __launch_bounds__(256) void gemm_bt(
    const bf16* __restrict__ A, const bf16* __restrict__ B,
    const float* __restrict__ bias, const float* __restrict__ resid,
    void* __restrict__ C, bf16* __restrict__ VT, const int* __restrict__ gidx,
    const int* __restrict__ counts, const int* __restrict__ offsets,
    int M, int N, int K) {
  constexpr int FM = BM / 32;
  constexpr int FN = BN / 32;
  constexpr int AL = BM / 32;
  constexpr int BL = BN / 32;
  int e = blockIdx.z;
  int Mcnt = M, base = 0;
  if (GROUPED) { Mcnt = counts[e]; base = offsets[e]; }
  // T1: bijective XCD swizzle (consecutive new-ids land on one XCD -> L2 reuse)
  int gx = gridDim.x;
  int nwg = gx * gridDim.y;
  int hb = blockIdx.y * gx + blockIdx.x;
  int wkid = (hb & 7) * (nwg >> 3) + (hb >> 3);
  int m0 = (wkid / gx) * BM, n0 = (wkid % gx) * BN;
  if (m0 >= Mcnt) return;
  const bf16* Bp = B + (size_t)e * N * K;
  const float* biasp = bias + (size_t)e * N;
  __shared__ __align__(16) bf16 As[BM * 64];
  __shared__ __align__(16) bf16 Bs[BN * 64];
  int tid = threadIdx.x, lane = tid & 63, wid = tid >> 6;
  int lr = lane & 15, lg = lane >> 4;
  int wr = (wid >> 1) * (BM / 2), wc = (wid & 1) * (BN / 2);
  const bf16* aptr[AL];
  const bf16* bptr[BL];
  int adst[AL], bdst[BL];
#pragma unroll
  for (int i = 0; i < AL; ++i) {
    int idx = i * 256 + tid;
    int r = idx >> 3, cb = idx & 7;
    int cbs = cb ^ (r & 7);
    int gr = m0 + r;
    int cl = gr < Mcnt ? gr : (Mcnt - 1);
    size_t arow = GATHER ? (size_t)gidx[base + cl] : (size_t)(base + cl);
    aptr[i] = A + arow * K + cbs * 8;
    adst[i] = idx * 8;
  }
#pragma unroll
  for (int i = 0; i < BL; ++i) {
    int idx = i * 256 + tid;
    int r = idx >> 3, cb = idx & 7;
    int cbs = cb ^ (r & 7);
    bptr[i] = Bp + (size_t)(n0 + r) * K + cbs * 8;
    bdst[i] = idx * 8;
  }
  int xa = lr & 7;
  int colk[2];
  colk[0] = (lg ^ xa) * 8;
  colk[1] = ((lg + 4) ^ xa) * 8;
  int arow_lds[FM], brow_lds[FN];
#pragma unroll
  for (int m_ = 0; m_ < FM; ++m_) arow_lds[m_] = (wr + m_ * 16 + lr) * 64;
#pragma unroll
  for (int n_ = 0; n_ < FN; ++n_) brow_lds[n_] = (wc + n_ * 16 + lr) * 64;

  f32x4 acc[FM][FN] = {};
  int nt = K >> 6;
  for (int t = 0; t < nt; ++t) {
    __syncthreads();
    int k0 = t << 6;
#pragma unroll
    for (int i = 0; i < AL; ++i) gload_lds16(aptr[i] + k0, &As[adst[i]]);
#pragma unroll
    for (int i = 0; i < BL; ++i) gload_lds16(bptr[i] + k0, &Bs[bdst[i]]);
    __syncthreads();
#pragma unroll
    for (int h = 0; h < 2; ++h) {
      short8 af[FM], bfg[FN];
#pragma unroll
      for (int m_ = 0; m_ < FM; ++m_)
        af[m_] = *(const short8*)&As[arow_lds[m_] + colk[h]];
#pragma unroll
      for (int n_ = 0; n_ < FN; ++n_)
        bfg[n_] = *(const short8*)&Bs[brow_lds[n_] + colk[h]];
#pragma unroll
      for (int m_ = 0; m_ < FM; ++m_)
#pragma unroll
        for (int n_ = 0; n_ < FN; ++n_)
          acc[m_][n_] = __builtin_amdgcn_mfma_f32_16x16x32_bf16(af[m_], bfg[n_], acc[m_][n_], 0, 0, 0);
    }
  }
#pragma unroll
  for (int n_ = 0; n_ < FN; ++n_) {
    int acol = n0 + wc + n_ * 16 + lr;
    float bv = biasp[acol];
#pragma unroll
    for (int m_ = 0; m_ < FM; ++m_) {
      int rbase = m0 + wr + m_ * 16 + lg * 4;
#pragma unroll
      for (int q = 0; q < 4; ++q) {
        int gr = rbase + q;
        if (gr >= Mcnt) continue;
        size_t crow = (size_t)(base + gr);
        float v = acc[m_][n_][q] + bv;
        if (EPI == 1) {
          float z = 0.7978845608028654f * (v + 0.044715f * v * v * v);
          float t2 = __expf(2.f * z);
          v = v * (t2 / (t2 + 1.f));  // v * sigmoid(2z)
          ((bf16*)C)[crow * N + acol] = __float2bfloat16(v);
        } else if (EPI == 2) {
          ((float*)C)[crow * N + acol] = v + resid[crow * N + acol];
        } else if (EPI == 3) {
          if (acol < 2048) {
            ((bf16*)C)[crow * N + acol] = __float2bfloat16(v);
          } else {
            int dg = acol - 2048;
            int hh = dg >> 6, dd = dg & 63;
            int bb = (int)(crow >> 10), tt = (int)(crow & 1023);
            VT[(((size_t)bb * 16 + hh) * 64 + dd) * 1024 + tt] = __float2bfloat16(v);
          }
        } else {
          ((bf16*)C)[crow * N + acol] = __float2bfloat16(v);
        }
      }
    }
  }
}

// ---- causal flash attention: paired q-tiles, KVBLK=128 ----------------------
__global__ __launch_bounds__(256) void attn_kernel(const bf16* __restrict__ qkv,
                                                   const bf16* __restrict__ vt,
                                                   bf16* __restrict__ out) {
  constexpr int T = 1024, QS = 3072;
  int bh = blockIdx.y;
  int b = bh >> 4, h = bh & 15;
  __shared__ __align__(16) bf16 Ks[128][72];
  __shared__ __align__(16) bf16 Vs[64][136];
  __shared__ __align__(16) bf16 Pl[4][16][72];
  int tid = threadIdx.x, lane = tid & 63, wid = tid >> 6;
  int lr = lane & 15, lg = lane >> 4;
  const size_t rowb = (size_t)b * T;
  const float SC = 0.18033688011112042f;  // 0.125 * log2(e)
  int ksr[4], kscb[4];
  const bf16* kbase[4];
  int vr[4], vc[4];
  const bf16* vbase[4];
#pragma unroll
  for (int i = 0; i < 4; ++i) {
    int idx = tid + i * 256;
    ksr[i] = idx >> 3; kscb[i] = idx & 7;
    kbase[i] = qkv + (rowb + ksr[i]) * QS + 1024 + h * 64 + kscb[i] * 8;
    vr[i] = idx >> 4; vc[i] = idx & 15;
    vbase[i] = vt + ((size_t)bh * 64 + vr[i]) * T + vc[i] * 8;
  }
  for (int half = 0; half < 2; ++half) {
    int qt = (half == 0) ? blockIdx.x : (15 - blockIdx.x);
    int qrow0 = qt * 64 + wid * 16 + lg * 4;
    int qmax = qt * 64 + 63;
    const bf16* qp = qkv + (rowb + qt * 64 + wid * 16 + lr) * QS + h * 64;
    short8 qf0 = *(const short8*)(qp + lg * 8);
    short8 qf1 = *(const short8*)(qp + 32 + lg * 8);
    f32x4 o[4] = {};
    float mrow[4] = {-3e38f, -3e38f, -3e38f, -3e38f};
    float lrow[4] = {0.f, 0.f, 0.f, 0.f};
    int nkvb = (qt >> 1) + 1;
    short8 kreg[4], vreg[4];
#pragma unroll
    for (int i = 0; i < 4; ++i) {
      kreg[i] = *(const short8*)kbase[i];
      vreg[i] = *(const short8*)vbase[i];
    }
    for (int kvb = 0; kvb < nkvb; ++kvb) {
      __syncthreads();
#pragma unroll
      for (int i = 0; i < 4; ++i) {
        *(short8*)&Ks[ksr[i]][kscb[i] * 8] = kreg[i];
        *(short8*)&Vs[vr[i]][vc[i] * 8] = vreg[i];
      }
      __syncthreads();
      if (kvb + 1 < nkvb) {
#pragma unroll
        for (int i = 0; i < 4; ++i) {
          kreg[i] = *(const short8*)(kbase[i] + (size_t)(kvb + 1) * 128 * QS);
          vreg[i] = *(const short8*)(vbase[i] + (kvb + 1) * 128);
        }
      }
#pragma unroll
      for (int hs = 0; hs < 2; ++hs) {
        int kb0 = kvb * 128 + hs * 64;
        if (kb0 > qmax) break;
        f32x4 s[4];
#pragma unroll
        for (int nf = 0; nf < 4; ++nf) {
          f32x4 z = {0.f, 0.f, 0.f, 0.f};
          short8 k0 = *(const short8*)&Ks[hs * 64 + nf * 16 + lr][lg * 8];
          short8 k1 = *(const short8*)&Ks[hs * 64 + nf * 16 + lr][32 + lg * 8];
          z = __builtin_amdgcn_mfma_f32_16x16x32_bf16(qf0, k0, z, 0, 0, 0);
          z = __builtin_amdgcn_mfma_f32_16x16x32_bf16(qf1, k1, z, 0, 0, 0);
          s[nf] = z;
        }
#pragma unroll
        for (int nf = 0; nf < 4; ++nf)
#pragma unroll
          for (int q = 0; q < 4; ++q) {
            float v = s[nf][q] * SC;
            int key = kb0 + nf * 16 + lr;
            if (key > qrow0 + q) v = -1e9f;
            s[nf][q] = v;
          }
        float rs[4], resc[4];
#pragma unroll
        for (int q = 0; q < 4; ++q) {
          float v = fmaxf(fmaxf(s[0][q], s[1][q]), fmaxf(s[2][q], s[3][q]));
          v = fmaxf(v, __shfl_xor(v, 1));
          v = fmaxf(v, __shfl_xor(v, 2));
          v = fmaxf(v, __shfl_xor(v, 4));
          v = fmaxf(v, __shfl_xor(v, 8));
          float mn = fmaxf(mrow[q], v);
          resc[q] = __builtin_amdgcn_exp2f(mrow[q] - mn);
          mrow[q] = mn;
          rs[q] = 0.f;
        }
#pragma unroll
        for (int nf = 0; nf < 4; ++nf)
#pragma unroll
          for (int q = 0; q < 4; ++q) {
            float p = __builtin_amdgcn_exp2f(s[nf][q] - mrow[q]);
            rs[q] += p;
            Pl[wid][lg * 4 + q][nf * 16 + lr] = __float2bfloat16(p);
          }
#pragma unroll
        for (int q = 0; q < 4; ++q) {
          float v = rs[q];
          v += __shfl_xor(v, 1); v += __shfl_xor(v, 2);
          v += __shfl_xor(v, 4); v += __shfl_xor(v, 8);
          lrow[q] = lrow[q] * resc[q] + v;
          o[0][q] *= resc[q]; o[1][q] *= resc[q]; o[2][q] *= resc[q]; o[3][q] *= resc[q];
        }
        short8 pa0 = *(const short8*)&Pl[wid][lr][lg * 8];
        short8 pa1 = *(const short8*)&Pl[wid][lr][32 + lg * 8];
#pragma unroll
        for (int nf = 0; nf < 4; ++nf) {
          short8 v0 = *(const short8*)&Vs[nf * 16 + lr][hs * 64 + lg * 8];
          short8 v1 = *(const short8*)&Vs[nf * 16 + lr][hs * 64 + 32 + lg * 8];
          o[nf] = __builtin_amdgcn_mfma_f32_16x16x32_bf16(pa0, v0, o[nf], 0, 0, 0);
          o[nf] = __builtin_amdgcn_mfma_f32_16x16x32_bf16(pa1, v1, o[nf], 0, 0, 0);
        }
      }
    }
#pragma unroll
    for (int q = 0; q < 4; ++q) {
      float inv = 1.0f / lrow[q];
      size_t row = rowb + qrow0 + q;
#pragma unroll
      for (int nf = 0; nf < 4; ++nf)
        out[row * 1024 + h * 64 + nf * 16 + lr] = __float2bfloat16(o[nf][q] * inv);
    }
  }
}

// ---- router: fp32 LN + logits + top2; ALSO writes LN2 row as bf16 -----------
__global__ __launch_bounds__(64) void router_kernel(
    const float* __restrict__ x2, const float* __restrict__ sc,
    const float* __restrict__ bi, const float* __restrict__ rw,
    bf16* __restrict__ ln2h, float* __restrict__ probs,
    int* __restrict__ topk, float* __restrict__ gates) {
  int t = blockIdx.x, lane = threadIdx.x;
  const float* xr = x2 + (size_t)t * 1024;
  float xv[16];
  float s = 0.f, sq = 0.f;
#pragma unroll
  for (int i = 0; i < 4; ++i) {
    float4 v = ((const float4*)xr)[lane * 4 + i];
    xv[i * 4 + 0] = v.x; xv[i * 4 + 1] = v.y; xv[i * 4 + 2] = v.z; xv[i * 4 + 3] = v.w;
    s += v.x + v.y + v.z + v.w;
    sq += v.x * v.x + v.y * v.y + v.z * v.z + v.w * v.w;
  }
#pragma unroll
  for (int m = 1; m < 64; m <<= 1) { s += __shfl_xor(s, m); sq += __shfl_xor(sq, m); }
  float mu = s * (1.f / 1024.f);
  float rstd = rsqrtf(sq * (1.f / 1024.f) - mu * mu + 1e-6f);
  float a8[8] = {};
  short8 o0, o1;
#pragma unroll
  for (int i = 0; i < 16; ++i) {
    int d = lane * 16 + i;
    float y = (xv[i] - mu) * rstd * sc[d] + bi[d];
    if (i < 8) o0[i] = (short)f2bu(y); else o1[i - 8] = (short)f2bu(y);
    const float4* rr = (const float4*)(rw + (size_t)d * 8);
    float4 r0 = rr[0], r1 = rr[1];
    a8[0] += y * r0.x; a8[1] += y * r0.y; a8[2] += y * r0.z; a8[3] += y * r0.w;
    a8[4] += y * r1.x; a8[5] += y * r1.y; a8[6] += y * r1.z; a8[7] += y * r1.w;
  }
  *(short8*)&ln2h[(size_t)t * 1024 + lane * 16] = o0;
  *(short8*)&ln2h[(size_t)t * 1024 + lane * 16 + 8] = o1;
#pragma unroll
  for (int m = 1; m < 64; m <<= 1)
#pragma unroll
    for (int e = 0; e < 8; ++e) a8[e] += __shfl_xor(a8[e], m);
  if (lane == 0) {
    float mx = a8[0];
#pragma unroll
    for (int e = 1; e < 8; ++e) mx = fmaxf(mx, a8[e]);
    float ps = 0.f, pe[8];
#pragma unroll
    for (int e = 0; e < 8; ++e) { pe[e] = expf(a8[e] - mx); ps += pe[e]; }
    float inv = 1.f / ps;
#pragma unroll
    for (int e = 0; e < 8; ++e) probs[t * 8 + e] = pe[e] * inv;
    int i0 = 0; float v0 = a8[0];
#pragma unroll
    for (int e = 1; e < 8; ++e) if (a8[e] > v0) { v0 = a8[e]; i0 = e; }
    int i1 = -1; float v1 = -3e38f;
#pragma unroll
    for (int e = 0; e < 8; ++e) if (e != i0 && a8[e] > v1) { v1 = a8[e]; i1 = e; }
    float g1 = 1.f / (1.f + expf(v0 - v1));
    topk[t * 2] = i0; topk[t * 2 + 1] = i1;
    gates[t * 2] = 1.f - g1; gates[t * 2 + 1] = g1;
  }
}

// ---- fused count + assign: 8 blocks, each counts all then assigns expert e ---
__global__ __launch_bounds__(256) void assign_kernel(
    const int* __restrict__ topk, int* __restrict__ counts,
    int* __restrict__ offsets, int* __restrict__ rows_tok,
    int* __restrict__ pair_pos) {
  int e = blockIdx.x;
  int tid = threadIdx.x, lane = tid & 63, wid = tid >> 6;
  __shared__ int c[8];
  if (tid < 8) c[tid] = 0;
  __syncthreads();
  for (int p = tid; p < 8192; p += 256) atomicAdd(&c[topk[p]], 1);
  __syncthreads();
  int base = 0;
  for (int k = 0; k < 8; ++k) if (k < e) base += c[k];
  if (tid == 0) { counts[e] = c[e]; offsets[e] = base; }
  __shared__ int wsum[4];
  int run = 0;
  for (int start = 0; start < 8192; start += 256) {
    int p = start + tid;
    int f = (topk[p] == e) ? 1 : 0;
    int v = f;
#pragma unroll
    for (int o_ = 1; o_ < 64; o_ <<= 1) { int u = __shfl_up(v, o_); if (lane >= o_) v += u; }
    if (lane == 63) wsum[wid] = v;
    __syncthreads();
    int wbase = 0;
#pragma unroll
    for (int w = 0; w < 4; ++w) if (w < wid) wbase += wsum[w];
    int tot = wsum[0] + wsum[1] + wsum[2] + wsum[3];
    if (f) {
      int pos = base + run + wbase + v - 1;
      rows_tok[pos] = p >> 1;
      pair_pos[p] = pos;
    }
    run += tot;
    __syncthreads();
  }
}

// ---------------- final combine (+ fused aux loss in block 4096) --------------
__global__ __launch_bounds__(256) void combine_kernel(
    const float* __restrict__ x2, const bf16* __restrict__ eo,
    const float* __restrict__ gates, const int* __restrict__ pair_pos,
    const float* __restrict__ probs, const int* __restrict__ topk,
    float* __restrict__ out, float* __restrict__ aux_out) {
  int t = blockIdx.x, tid = threadIdx.x;
  if (t == 4096) {
    int lane = tid & 63, wid = tid >> 6;
    float P[8] = {}, Fc[8] = {};
    for (int tt = tid; tt < 4096; tt += 256) {
#pragma unroll
      for (int e = 0; e < 8; ++e) P[e] += probs[tt * 8 + e];
      Fc[topk[tt * 2]] += 1.f;
    }
#pragma unroll
    for (int m = 1; m < 64; m <<= 1)
#pragma unroll
      for (int e = 0; e < 8; ++e) { P[e] += __shfl_xor(P[e], m); Fc[e] += __shfl_xor(Fc[e], m); }
    __shared__ float sP[4][8], sF[4][8];
    if (lane == 0)
#pragma unroll
      for (int e = 0; e < 8; ++e) { sP[wid][e] = P[e]; sF[wid][e] = Fc[e]; }
    __syncthreads();
    if (tid == 0) {
      float aux = 0.f;
      for (int e = 0; e < 8; ++e) {
        float p = (sP[0][e] + sP[1][e] + sP[2][e] + sP[3][e]) * (1.f / 4096.f);
        float f = (sF[0][e] + sF[1][e] + sF[2][e] + sF[3][e]) * (1.f / 4096.f);
        aux += f * p;
      }
      aux_out[0] = 8.f * aux;
    }
    return;
  }
  float g0 = gates[t * 2], g1 = gates[t * 2 + 1];
  size_t p0 = (size_t)pair_pos[t * 2] * 1024, p1 = (size_t)pair_pos[t * 2 + 1] * 1024;
  size_t rb = (size_t)t * 1024;
#pragma unroll
  for (int i = 0; i < 4; ++i) {
    int d = tid + i * 256;
    out[rb + d] = x2[rb + d] + g0 * __bfloat162float(eo[p0 + d]) + g1 * __bfloat162float(eo[p1 + d]);
  }
}

// ---------------- launch -------------------------------------------------------
extern "C" void kernel_launch(void* const* d_in, const int* in_sizes, int n_in,
                              void* d_out, int out_size, void* d_ws, size_t ws_size,
                              hipStream_t stream) {
  (void)in_sizes; (void)n_in; (void)out_size; (void)ws_size;
  const float* x    = (const float*)d_in[0];
  const float* ln1s = (const float*)d_in[1];
  const float* ln1b = (const float*)d_in[2];
  const float* qkvw = (const float*)d_in[3];
  const float* qkvb = (const float*)d_in[4];
  const float* outw = (const float*)d_in[5];
  const float* outb = (const float*)d_in[6];
  const float* ln2s = (const float*)d_in[7];
  const float* ln2b = (const float*)d_in[8];
  const float* rw   = (const float*)d_in[9];
  const float* w1   = (const float*)d_in[10];
  const float* b1   = (const float*)d_in[11];
  const float* w2   = (const float*)d_in[12];
  const float* b2   = (const float*)d_in[13];

  char* ws = (char*)d_ws;
  size_t off = 0;
  auto alloc = [&](size_t bytes) -> char* {
    char* p = ws + off; off += (bytes + 255) & ~(size_t)255; return p;
  };
  bf16* qkvw_t  = (bf16*)alloc(3072ull * 1024 * 2);
  bf16* outw_t  = (bf16*)alloc(1024ull * 1024 * 2);
  bf16* w1_t    = (bf16*)alloc(8ull * 2048 * 1024 * 2);
  bf16* w2_t    = (bf16*)alloc(8ull * 1024 * 2048 * 2);
  bf16* h1      = (bf16*)alloc(4096ull * 1024 * 2);
  bf16* qkv     = (bf16*)alloc(4096ull * 3072 * 2);
  bf16* vtb     = (bf16*)alloc(64ull * 64 * 1024 * 2);
  bf16* attn_o  = (bf16*)alloc(4096ull * 1024 * 2);
  float* x2     = (float*)alloc(4096ull * 1024 * 4);
  bf16* ln2h    = (bf16*)alloc(4096ull * 1024 * 2);
  float* probs  = (float*)alloc(4096ull * 8 * 4);
  float* gates  = (float*)alloc(4096ull * 2 * 4);
  int* topk     = (int*)alloc(8192 * 4);
  int* counts   = (int*)alloc(64 * 4);
  int* offsets  = (int*)alloc(64 * 4);
  int* rows_tok = (int*)alloc(8192 * 4);
  int* pair_pos = (int*)alloc(8192 * 4);
  bf16* h_buf   = (bf16*)alloc(8192ull * 2048 * 2);
  bf16* eo      = (bf16*)alloc(8192ull * 1024 * 2);

  transpose4<<<9216, 256, 0, stream>>>(qkvw, qkvw_t, outw, outw_t, w1, w1_t, w2, w2_t);

  ln_kernel<<<4096, 256, 0, stream>>>(x, ln1s, ln1b, h1);

  // QKV: 64x128 tiles, grid 24x64=1536 (%8==0)
  gemm_bt<64, 128, 3, false, false><<<dim3(3072 / 128, 4096 / 64, 1), 256, 0, stream>>>(
      h1, qkvw_t, qkvb, nullptr, qkv, vtb, nullptr, nullptr, nullptr, 4096, 3072, 1024);

  attn_kernel<<<dim3(8, 64), 256, 0, stream>>>(qkv, vtb, attn_o);

  // out-proj: 64x64 tiles, grid 16x64=1024 (%8==0) -> 4 blocks/CU
  gemm_bt<64, 64, 2, false, false><<<dim3(1024 / 64, 4096 / 64, 1), 256, 0, stream>>>(
      attn_o, outw_t, outb, x, x2, nullptr, nullptr, nullptr, nullptr, 4096, 1024, 1024);

  router_kernel<<<4096, 64, 0, stream>>>(x2, ln2s, ln2b, rw, ln2h, probs, topk, gates);

  assign_kernel<<<8, 256, 0, stream>>>(topk, counts, offsets, rows_tok, pair_pos);

  // MoE GEMM1: 64x128, grid 16x128=2048 per expert (%8==0)
  gemm_bt<64, 128, 1, true, true><<<dim3(2048 / 128, 8192 / 64, 8), 256, 0, stream>>>(
      ln2h, w1_t, b1, nullptr, h_buf, nullptr, rows_tok, counts, offsets, 8192, 2048, 1024);

  // MoE GEMM2: 64x128, grid 8x128=1024 per expert (%8==0)
  gemm_bt<64, 128, 0, false, true><<<dim3(1024 / 128, 8192 / 64, 8), 256, 0, stream>>>(
      h_buf, w2_t, b2, nullptr, eo, nullptr, nullptr, counts, offsets, 8192, 1024, 2048);

  combine_kernel<<<4097, 256, 0, stream>>>(x2, eo, gates, pair_pos, probs, topk,
                                           (float*)d_out, (float*)d_out + 4194304);
}

// Round 17
// 350.006 us; speedup vs baseline: 2.4738x; 2.4738x over previous
//
#include <hip/hip_runtime.h>
#include <hip/hip_bf16.h>

using bf16 = __hip_bfloat16;
typedef __attribute__((ext_vector_type(8))) short short8;
typedef __attribute__((ext_vector_type(4))) float f32x4;

__device__ __forceinline__ unsigned short f2bu(float x) {
  union { bf16 b; unsigned short u; } cv; cv.b = __float2bfloat16(x); return cv.u;
}

__device__ __forceinline__ void gload_lds16(const bf16* g, bf16* l) {
  __builtin_amdgcn_global_load_lds(
      (const __attribute__((address_space(1))) void*)g,
      (__attribute__((address_space(3))) void*)l, 16, 0, 0);
}

// ---- merged transpose + fp32->bf16 (4 weight tensors in one launch) ---------
__global__ __launch_bounds__(256) void transpose4(
    const float* __restrict__ i0, bf16* __restrict__ o0,
    const float* __restrict__ i1, bf16* __restrict__ o1,
    const float* __restrict__ i2, bf16* __restrict__ o2,
    const float* __restrict__ i3, bf16* __restrict__ o3) {
  __shared__ float tile[64][65];
  int bid = blockIdx.x;
  const float* in; bf16* out; int R, C, bx, by, bz = 0;
  if (bid < 768)        { in = i0; out = o0; R = 1024; C = 3072; bx = bid % 48; by = bid / 48; }
  else if (bid < 1024)  { int b = bid - 768;  in = i1; out = o1; R = 1024; C = 1024; bx = b % 16; by = b / 16; }
  else if (bid < 5120)  { int b = bid - 1024; in = i2; out = o2; R = 1024; C = 2048; bz = b >> 9; int lb = b & 511; bx = lb % 32; by = lb / 32; }
  else                  { int b = bid - 5120; in = i3; out = o3; R = 2048; C = 1024; bz = b >> 9; int lb = b & 511; bx = lb % 16; by = lb / 16; }
  size_t bo = (size_t)bz * R * C;
  in += bo; out += bo;
  int c0 = bx * 64, r0 = by * 64;
  int tx = threadIdx.x & 15, ty = threadIdx.x >> 4;  // 16 x 16
#pragma unroll
  for (int i = 0; i < 4; ++i) {
    float4 v = *(const float4*)&in[(size_t)(r0 + ty + i * 16) * C + c0 + tx * 4];
    tile[ty + i * 16][tx * 4 + 0] = v.x;
    tile[ty + i * 16][tx * 4 + 1] = v.y;
    tile[ty + i * 16][tx * 4 + 2] = v.z;
    tile[ty + i * 16][tx * 4 + 3] = v.w;
  }
  __syncthreads();
  int rr0 = (threadIdx.x & 15) * 4;
  int cg = threadIdx.x >> 4;
#pragma unroll
  for (int jj = 0; jj < 4; ++jj) {
    int cc = jj * 16 + cg;
    ushort4 o;
    o.x = f2bu(tile[rr0 + 0][cc]);
    o.y = f2bu(tile[rr0 + 1][cc]);
    o.z = f2bu(tile[rr0 + 2][cc]);
    o.w = f2bu(tile[rr0 + 3][cc]);
    *(ushort4*)&out[(size_t)(c0 + cc) * R + r0 + rr0] = o;
  }
}

// ---------------- LayerNorm: fp32 in -> bf16 out (row = 1024) ----------------
__global__ __launch_bounds__(256) void ln_kernel(
    const float* __restrict__ in, const float* __restrict__ sc,
    const float* __restrict__ bi, bf16* __restrict__ out) {
  int row = blockIdx.x, tid = threadIdx.x;
  const float4* xr = (const float4*)(in + (size_t)row * 1024);
  float4 v = xr[tid];
  float s = v.x + v.y + v.z + v.w;
  float sq = v.x * v.x + v.y * v.y + v.z * v.z + v.w * v.w;
#pragma unroll
  for (int m = 1; m < 64; m <<= 1) { s += __shfl_xor(s, m); sq += __shfl_xor(sq, m); }
  __shared__ float red[8];
  int wid = tid >> 6, lane = tid & 63;
  if (lane == 0) { red[wid] = s; red[4 + wid] = sq; }
  __syncthreads();
  s = red[0] + red[1] + red[2] + red[3];
  sq = red[4] + red[5] + red[6] + red[7];
  float mu = s * (1.f / 1024.f);
  float rstd = rsqrtf(sq * (1.f / 1024.f) - mu * mu + 1e-6f);
  float4 scv = ((const float4*)sc)[tid];
  float4 biv = ((const float4*)bi)[tid];
  ushort4 ov;
  ov.x = f2bu((v.x - mu) * rstd * scv.x + biv.x);
  ov.y = f2bu((v.y - mu) * rstd * scv.y + biv.y);
  ov.z = f2bu((v.z - mu) * rstd * scv.z + biv.z);
  ov.w = f2bu((v.w - mu) * rstd * scv.w + biv.w);
  ((ushort4*)(out + (size_t)row * 1024))[tid] = ov;
}

// ---- GEMM: single-buffer m97-structure, tile BMxBN, 4 waves (2x2) ----------
template <int BM, int BN, int EPI, bool GATHER, bool GROUPED>
__global__ __launch_bounds__(256) void gemm_bt(
    const bf16* __restrict__ A, const bf16* __restrict__ B,
    const float* __restrict__ bias, const float* __restrict__ resid,
    void* __restrict__ C, bf16* __restrict__ VT, const int* __restrict__ gidx,
    const int* __restrict__ counts, const int* __restrict__ offsets,
    int M, int N, int K) {
  constexpr int FM = BM / 32;
  constexpr int FN = BN / 32;
  constexpr int AL = BM / 32;
  constexpr int BL = BN / 32;
  int e = blockIdx.z;
  int Mcnt = M, base = 0;
  if (GROUPED) { Mcnt = counts[e]; base = offsets[e]; }
  int m0 = blockIdx.y * BM, n0 = blockIdx.x * BN;
  if (m0 >= Mcnt) return;
  const bf16* Bp = B + (size_t)e * N * K;
  const float* biasp = bias + (size_t)e * N;
  __shared__ __align__(16) bf16 As[BM * 64];
  __shared__ __align__(16) bf16 Bs[BN * 64];
  int tid = threadIdx.x, lane = tid & 63, wid = tid >> 6;
  int lr = lane & 15, lg = lane >> 4;
  int wr = (wid >> 1) * (BM / 2), wc = (wid & 1) * (BN / 2);
  const bf16* aptr[AL];
  const bf16* bptr[BL];
  int adst[AL], bdst[BL];
#pragma unroll
  for (int i = 0; i < AL; ++i) {
    int idx = i * 256 + tid;
    int r = idx >> 3, cb = idx & 7;
    int cbs = cb ^ (r & 7);
    int gr = m0 + r;
    int cl = gr < Mcnt ? gr : (Mcnt - 1);
    size_t arow = GATHER ? (size_t)gidx[base + cl] : (size_t)(base + cl);
    aptr[i] = A + arow * K + cbs * 8;
    adst[i] = idx * 8;
  }
#pragma unroll
  for (int i = 0; i < BL; ++i) {
    int idx = i * 256 + tid;
    int r = idx >> 3, cb = idx & 7;
    int cbs = cb ^ (r & 7);
    bptr[i] = Bp + (size_t)(n0 + r) * K + cbs * 8;
    bdst[i] = idx * 8;
  }
  int xa = lr & 7;
  int colk[2];
  colk[0] = (lg ^ xa) * 8;
  colk[1] = ((lg + 4) ^ xa) * 8;
  int arow_lds[FM], brow_lds[FN];
#pragma unroll
  for (int m_ = 0; m_ < FM; ++m_) arow_lds[m_] = (wr + m_ * 16 + lr) * 64;
#pragma unroll
  for (int n_ = 0; n_ < FN; ++n_) brow_lds[n_] = (wc + n_ * 16 + lr) * 64;

  f32x4 acc[FM][FN] = {};
  int nt = K >> 6;
  for (int t = 0; t < nt; ++t) {
    __syncthreads();
    int k0 = t << 6;
#pragma unroll
    for (int i = 0; i < AL; ++i) gload_lds16(aptr[i] + k0, &As[adst[i]]);
#pragma unroll
    for (int i = 0; i < BL; ++i) gload_lds16(bptr[i] + k0, &Bs[bdst[i]]);
    __syncthreads();
#pragma unroll
    for (int h = 0; h < 2; ++h) {
      short8 af[FM], bfg[FN];
#pragma unroll
      for (int m_ = 0; m_ < FM; ++m_)
        af[m_] = *(const short8*)&As[arow_lds[m_] + colk[h]];
#pragma unroll
      for (int n_ = 0; n_ < FN; ++n_)
        bfg[n_] = *(const short8*)&Bs[brow_lds[n_] + colk[h]];
#pragma unroll
      for (int m_ = 0; m_ < FM; ++m_)
#pragma unroll
        for (int n_ = 0; n_ < FN; ++n_)
          acc[m_][n_] = __builtin_amdgcn_mfma_f32_16x16x32_bf16(af[m_], bfg[n_], acc[m_][n_], 0, 0, 0);
    }
  }
#pragma unroll
  for (int n_ = 0; n_ < FN; ++n_) {
    int acol = n0 + wc + n_ * 16 + lr;
    float bv = biasp[acol];
#pragma unroll
    for (int m_ = 0; m_ < FM; ++m_) {
      int rbase = m0 + wr + m_ * 16 + lg * 4;
#pragma unroll
      for (int q = 0; q < 4; ++q) {
        int gr = rbase + q;
        if (gr >= Mcnt) continue;
        size_t crow = (size_t)(base + gr);
        float v = acc[m_][n_][q] + bv;
        if (EPI == 1) {
          float z = 0.7978845608028654f * (v + 0.044715f * v * v * v);
          float t2 = __expf(2.f * z);
          v = v * (t2 / (t2 + 1.f));  // v * sigmoid(2z)
          ((bf16*)C)[crow * N + acol] = __float2bfloat16(v);
        } else if (EPI == 2) {
          ((float*)C)[crow * N + acol] = v + resid[crow * N + acol];
        } else if (EPI == 3) {
          if (acol < 2048) {
            ((bf16*)C)[crow * N + acol] = __float2bfloat16(v);
          } else {
            int dg = acol - 2048;
            int hh = dg >> 6, dd = dg & 63;
            int bb = (int)(crow >> 10), tt = (int)(crow & 1023);
            VT[(((size_t)bb * 16 + hh) * 64 + dd) * 1024 + tt] = __float2bfloat16(v);
          }
        } else {
          ((bf16*)C)[crow * N + acol] = __float2bfloat16(v);
        }
      }
    }
  }
}

// ---- causal flash attention: paired q-tiles, KVBLK=128 ----------------------
__global__ __launch_bounds__(256) void attn_kernel(const bf16* __restrict__ qkv,
                                                   const bf16* __restrict__ vt,
                                                   bf16* __restrict__ out) {
  constexpr int T = 1024, QS = 3072;
  int bh = blockIdx.y;
  int b = bh >> 4, h = bh & 15;
  __shared__ __align__(16) bf16 Ks[128][72];
  __shared__ __align__(16) bf16 Vs[64][136];
  __shared__ __align__(16) bf16 Pl[4][16][72];
  int tid = threadIdx.x, lane = tid & 63, wid = tid >> 6;
  int lr = lane & 15, lg = lane >> 4;
  const size_t rowb = (size_t)b * T;
  const float SC = 0.18033688011112042f;  // 0.125 * log2(e)
  int ksr[4], kscb[4];
  const bf16* kbase[4];
  int vr[4], vc[4];
  const bf16* vbase[4];
#pragma unroll
  for (int i = 0; i < 4; ++i) {
    int idx = tid + i * 256;
    ksr[i] = idx >> 3; kscb[i] = idx & 7;
    kbase[i] = qkv + (rowb + ksr[i]) * QS + 1024 + h * 64 + kscb[i] * 8;
    vr[i] = idx >> 4; vc[i] = idx & 15;
    vbase[i] = vt + ((size_t)bh * 64 + vr[i]) * T + vc[i] * 8;
  }
  for (int half = 0; half < 2; ++half) {
    int qt = (half == 0) ? blockIdx.x : (15 - blockIdx.x);
    int qrow0 = qt * 64 + wid * 16 + lg * 4;
    int qmax = qt * 64 + 63;
    const bf16* qp = qkv + (rowb + qt * 64 + wid * 16 + lr) * QS + h * 64;
    short8 qf0 = *(const short8*)(qp + lg * 8);
    short8 qf1 = *(const short8*)(qp + 32 + lg * 8);
    f32x4 o[4] = {};
    float mrow[4] = {-3e38f, -3e38f, -3e38f, -3e38f};
    float lrow[4] = {0.f, 0.f, 0.f, 0.f};
    int nkvb = (qt >> 1) + 1;
    short8 kreg[4], vreg[4];
#pragma unroll
    for (int i = 0; i < 4; ++i) {
      kreg[i] = *(const short8*)kbase[i];
      vreg[i] = *(const short8*)vbase[i];
    }
    for (int kvb = 0; kvb < nkvb; ++kvb) {
      __syncthreads();
#pragma unroll
      for (int i = 0; i < 4; ++i) {
        *(short8*)&Ks[ksr[i]][kscb[i] * 8] = kreg[i];
        *(short8*)&Vs[vr[i]][vc[i] * 8] = vreg[i];
      }
      __syncthreads();
      if (kvb + 1 < nkvb) {
#pragma unroll
        for (int i = 0; i < 4; ++i) {
          kreg[i] = *(const short8*)(kbase[i] + (size_t)(kvb + 1) * 128 * QS);
          vreg[i] = *(const short8*)(vbase[i] + (kvb + 1) * 128);
        }
      }
#pragma unroll
      for (int hs = 0; hs < 2; ++hs) {
        int kb0 = kvb * 128 + hs * 64;
        if (kb0 > qmax) break;
        f32x4 s[4];
#pragma unroll
        for (int nf = 0; nf < 4; ++nf) {
          f32x4 z = {0.f, 0.f, 0.f, 0.f};
          short8 k0 = *(const short8*)&Ks[hs * 64 + nf * 16 + lr][lg * 8];
          short8 k1 = *(const short8*)&Ks[hs * 64 + nf * 16 + lr][32 + lg * 8];
          z = __builtin_amdgcn_mfma_f32_16x16x32_bf16(qf0, k0, z, 0, 0, 0);
          z = __builtin_amdgcn_mfma_f32_16x16x32_bf16(qf1, k1, z, 0, 0, 0);
          s[nf] = z;
        }
#pragma unroll
        for (int nf = 0; nf < 4; ++nf)
#pragma unroll
          for (int q = 0; q < 4; ++q) {
            float v = s[nf][q] * SC;
            int key = kb0 + nf * 16 + lr;
            if (key > qrow0 + q) v = -1e9f;
            s[nf][q] = v;
          }
        float rs[4], resc[4];
#pragma unroll
        for (int q = 0; q < 4; ++q) {
          float v = fmaxf(fmaxf(s[0][q], s[1][q]), fmaxf(s[2][q], s[3][q]));
          v = fmaxf(v, __shfl_xor(v, 1));
          v = fmaxf(v, __shfl_xor(v, 2));
          v = fmaxf(v, __shfl_xor(v, 4));
          v = fmaxf(v, __shfl_xor(v, 8));
          float mn = fmaxf(mrow[q], v);
          resc[q] = __builtin_amdgcn_exp2f(mrow[q] - mn);
          mrow[q] = mn;
          rs[q] = 0.f;
        }
#pragma unroll
        for (int nf = 0; nf < 4; ++nf)
#pragma unroll
          for (int q = 0; q < 4; ++q) {
            float p = __builtin_amdgcn_exp2f(s[nf][q] - mrow[q]);
            rs[q] += p;
            Pl[wid][lg * 4 + q][nf * 16 + lr] = __float2bfloat16(p);
          }
#pragma unroll
        for (int q = 0; q < 4; ++q) {
          float v = rs[q];
          v += __shfl_xor(v, 1); v += __shfl_xor(v, 2);
          v += __shfl_xor(v, 4); v += __shfl_xor(v, 8);
          lrow[q] = lrow[q] * resc[q] + v;
          o[0][q] *= resc[q]; o[1][q] *= resc[q]; o[2][q] *= resc[q]; o[3][q] *= resc[q];
        }
        short8 pa0 = *(const short8*)&Pl[wid][lr][lg * 8];
        short8 pa1 = *(const short8*)&Pl[wid][lr][32 + lg * 8];
#pragma unroll
        for (int nf = 0; nf < 4; ++nf) {
          short8 v0 = *(const short8*)&Vs[nf * 16 + lr][hs * 64 + lg * 8];
          short8 v1 = *(const short8*)&Vs[nf * 16 + lr][hs * 64 + 32 + lg * 8];
          o[nf] = __builtin_amdgcn_mfma_f32_16x16x32_bf16(pa0, v0, o[nf], 0, 0, 0);
          o[nf] = __builtin_amdgcn_mfma_f32_16x16x32_bf16(pa1, v1, o[nf], 0, 0, 0);
        }
      }
    }
#pragma unroll
    for (int q = 0; q < 4; ++q) {
      float inv = 1.0f / lrow[q];
      size_t row = rowb + qrow0 + q;
#pragma unroll
      for (int nf = 0; nf < 4; ++nf)
        out[row * 1024 + h * 64 + nf * 16 + lr] = __float2bfloat16(o[nf][q] * inv);
    }
  }
}

// ---- router: fp32 LN + logits + top2; ALSO writes LN2 row as bf16 -----------
__global__ __launch_bounds__(64) void router_kernel(
    const float* __restrict__ x2, const float* __restrict__ sc,
    const float* __restrict__ bi, const float* __restrict__ rw,
    bf16* __restrict__ ln2h, float* __restrict__ probs,
    int* __restrict__ topk, float* __restrict__ gates) {
  int t = blockIdx.x, lane = threadIdx.x;
  const float* xr = x2 + (size_t)t * 1024;
  float xv[16];
  float s = 0.f, sq = 0.f;
#pragma unroll
  for (int i = 0; i < 4; ++i) {
    float4 v = ((const float4*)xr)[lane * 4 + i];
    xv[i * 4 + 0] = v.x; xv[i * 4 + 1] = v.y; xv[i * 4 + 2] = v.z; xv[i * 4 + 3] = v.w;
    s += v.x + v.y + v.z + v.w;
    sq += v.x * v.x + v.y * v.y + v.z * v.z + v.w * v.w;
  }
#pragma unroll
  for (int m = 1; m < 64; m <<= 1) { s += __shfl_xor(s, m); sq += __shfl_xor(sq, m); }
  float mu = s * (1.f / 1024.f);
  float rstd = rsqrtf(sq * (1.f / 1024.f) - mu * mu + 1e-6f);
  float a8[8] = {};
  short8 o0, o1;
#pragma unroll
  for (int i = 0; i < 16; ++i) {
    int d = lane * 16 + i;
    float y = (xv[i] - mu) * rstd * sc[d] + bi[d];
    if (i < 8) o0[i] = (short)f2bu(y); else o1[i - 8] = (short)f2bu(y);
    const float4* rr = (const float4*)(rw + (size_t)d * 8);
    float4 r0 = rr[0], r1 = rr[1];
    a8[0] += y * r0.x; a8[1] += y * r0.y; a8[2] += y * r0.z; a8[3] += y * r0.w;
    a8[4] += y * r1.x; a8[5] += y * r1.y; a8[6] += y * r1.z; a8[7] += y * r1.w;
  }
  *(short8*)&ln2h[(size_t)t * 1024 + lane * 16] = o0;
  *(short8*)&ln2h[(size_t)t * 1024 + lane * 16 + 8] = o1;
#pragma unroll
  for (int m = 1; m < 64; m <<= 1)
#pragma unroll
    for (int e = 0; e < 8; ++e) a8[e] += __shfl_xor(a8[e], m);
  if (lane == 0) {
    float mx = a8[0];
#pragma unroll
    for (int e = 1; e < 8; ++e) mx = fmaxf(mx, a8[e]);
    float ps = 0.f, pe[8];
#pragma unroll
    for (int e = 0; e < 8; ++e) { pe[e] = expf(a8[e] - mx); ps += pe[e]; }
    float inv = 1.f / ps;
#pragma unroll
    for (int e = 0; e < 8; ++e) probs[t * 8 + e] = pe[e] * inv;
    int i0 = 0; float v0 = a8[0];
#pragma unroll
    for (int e = 1; e < 8; ++e) if (a8[e] > v0) { v0 = a8[e]; i0 = e; }
    int i1 = -1; float v1 = -3e38f;
#pragma unroll
    for (int e = 0; e < 8; ++e) if (e != i0 && a8[e] > v1) { v1 = a8[e]; i1 = e; }
    float g1 = 1.f / (1.f + expf(v0 - v1));
    topk[t * 2] = i0; topk[t * 2 + 1] = i1;
    gates[t * 2] = 1.f - g1; gates[t * 2 + 1] = g1;
  }
}

// ---- fused count + assign: 8 blocks, each counts all then assigns expert e ---
__global__ __launch_bounds__(256) void assign_kernel(
    const int* __restrict__ topk, int* __restrict__ counts,
    int* __restrict__ offsets, int* __restrict__ rows_tok,
    int* __restrict__ pair_pos) {
  int e = blockIdx.x;
  int tid = threadIdx.x, lane = tid & 63, wid = tid >> 6;
  __shared__ int c[8];
  if (tid < 8) c[tid] = 0;
  __syncthreads();
  for (int p = tid; p < 8192; p += 256) atomicAdd(&c[topk[p]], 1);
  __syncthreads();
  int base = 0;
  for (int k = 0; k < 8; ++k) if (k < e) base += c[k];
  if (tid == 0) { counts[e] = c[e]; offsets[e] = base; }
  __shared__ int wsum[4];
  int run = 0;
  for (int start = 0; start < 8192; start += 256) {
    int p = start + tid;
    int f = (topk[p] == e) ? 1 : 0;
    int v = f;
#pragma unroll
    for (int o_ = 1; o_ < 64; o_ <<= 1) { int u = __shfl_up(v, o_); if (lane >= o_) v += u; }
    if (lane == 63) wsum[wid] = v;
    __syncthreads();
    int wbase = 0;
#pragma unroll
    for (int w = 0; w < 4; ++w) if (w < wid) wbase += wsum[w];
    int tot = wsum[0] + wsum[1] + wsum[2] + wsum[3];
    if (f) {
      int pos = base + run + wbase + v - 1;
      rows_tok[pos] = p >> 1;
      pair_pos[p] = pos;
    }
    run += tot;
    __syncthreads();
  }
}

// ---------------- final combine (+ fused aux loss in block 4096) --------------
__global__ __launch_bounds__(256) void combine_kernel(
    const float* __restrict__ x2, const bf16* __restrict__ eo,
    const float* __restrict__ gates, const int* __restrict__ pair_pos,
    const float* __restrict__ probs, const int* __restrict__ topk,
    float* __restrict__ out, float* __restrict__ aux_out) {
  int t = blockIdx.x, tid = threadIdx.x;
  if (t == 4096) {
    int lane = tid & 63, wid = tid >> 6;
    float P[8] = {}, Fc[8] = {};
    for (int tt = tid; tt < 4096; tt += 256) {
#pragma unroll
      for (int e = 0; e < 8; ++e) P[e] += probs[tt * 8 + e];
      Fc[topk[tt * 2]] += 1.f;
    }
#pragma unroll
    for (int m = 1; m < 64; m <<= 1)
#pragma unroll
      for (int e = 0; e < 8; ++e) { P[e] += __shfl_xor(P[e], m); Fc[e] += __shfl_xor(Fc[e], m); }
    __shared__ float sP[4][8], sF[4][8];
    if (lane == 0)
#pragma unroll
      for (int e = 0; e < 8; ++e) { sP[wid][e] = P[e]; sF[wid][e] = Fc[e]; }
    __syncthreads();
    if (tid == 0) {
      float aux = 0.f;
      for (int e = 0; e < 8; ++e) {
        float p = (sP[0][e] + sP[1][e] + sP[2][e] + sP[3][e]) * (1.f / 4096.f);
        float f = (sF[0][e] + sF[1][e] + sF[2][e] + sF[3][e]) * (1.f / 4096.f);
        aux += f * p;
      }
      aux_out[0] = 8.f * aux;
    }
    return;
  }
  float g0 = gates[t * 2], g1 = gates[t * 2 + 1];
  size_t p0 = (size_t)pair_pos[t * 2] * 1024, p1 = (size_t)pair_pos[t * 2 + 1] * 1024;
  size_t rb = (size_t)t * 1024;
#pragma unroll
  for (int i = 0; i < 4; ++i) {
    int d = tid + i * 256;
    out[rb + d] = x2[rb + d] + g0 * __bfloat162float(eo[p0 + d]) + g1 * __bfloat162float(eo[p1 + d]);
  }
}

// ---------------- launch -------------------------------------------------------
extern "C" void kernel_launch(void* const* d_in, const int* in_sizes, int n_in,
                              void* d_out, int out_size, void* d_ws, size_t ws_size,
                              hipStream_t stream) {
  (void)in_sizes; (void)n_in; (void)out_size; (void)ws_size;
  const float* x    = (const float*)d_in[0];
  const float* ln1s = (const float*)d_in[1];
  const float* ln1b = (const float*)d_in[2];
  const float* qkvw = (const float*)d_in[3];
  const float* qkvb = (const float*)d_in[4];
  const float* outw = (const float*)d_in[5];
  const float* outb = (const float*)d_in[6];
  const float* ln2s = (const float*)d_in[7];
  const float* ln2b = (const float*)d_in[8];
  const float* rw   = (const float*)d_in[9];
  const float* w1   = (const float*)d_in[10];
  const float* b1   = (const float*)d_in[11];
  const float* w2   = (const float*)d_in[12];
  const float* b2   = (const float*)d_in[13];

  char* ws = (char*)d_ws;
  size_t off = 0;
  auto alloc = [&](size_t bytes) -> char* {
    char* p = ws + off; off += (bytes + 255) & ~(size_t)255; return p;
  };
  bf16* qkvw_t  = (bf16*)alloc(3072ull * 1024 * 2);
  bf16* outw_t  = (bf16*)alloc(1024ull * 1024 * 2);
  bf16* w1_t    = (bf16*)alloc(8ull * 2048 * 1024 * 2);
  bf16* w2_t    = (bf16*)alloc(8ull * 1024 * 2048 * 2);
  bf16* h1      = (bf16*)alloc(4096ull * 1024 * 2);
  bf16* qkv     = (bf16*)alloc(4096ull * 3072 * 2);
  bf16* vtb     = (bf16*)alloc(64ull * 64 * 1024 * 2);
  bf16* attn_o  = (bf16*)alloc(4096ull * 1024 * 2);
  float* x2     = (float*)alloc(4096ull * 1024 * 4);
  bf16* ln2h    = (bf16*)alloc(4096ull * 1024 * 2);
  float* probs  = (float*)alloc(4096ull * 8 * 4);
  float* gates  = (float*)alloc(4096ull * 2 * 4);
  int* topk     = (int*)alloc(8192 * 4);
  int* counts   = (int*)alloc(64 * 4);
  int* offsets  = (int*)alloc(64 * 4);
  int* rows_tok = (int*)alloc(8192 * 4);
  int* pair_pos = (int*)alloc(8192 * 4);
  bf16* h_buf   = (bf16*)alloc(8192ull * 2048 * 2);
  bf16* eo      = (bf16*)alloc(8192ull * 1024 * 2);

  transpose4<<<9216, 256, 0, stream>>>(qkvw, qkvw_t, outw, outw_t, w1, w1_t, w2, w2_t);

  ln_kernel<<<4096, 256, 0, stream>>>(x, ln1s, ln1b, h1);

  gemm_bt<64, 128, 3, false, false><<<dim3(3072 / 128, 4096 / 64, 1), 256, 0, stream>>>(
      h1, qkvw_t, qkvb, nullptr, qkv, vtb, nullptr, nullptr, nullptr, 4096, 3072, 1024);

  attn_kernel<<<dim3(8, 64), 256, 0, stream>>>(qkv, vtb, attn_o);

  gemm_bt<64, 128, 2, false, false><<<dim3(1024 / 128, 4096 / 64, 1), 256, 0, stream>>>(
      attn_o, outw_t, outb, x, x2, nullptr, nullptr, nullptr, nullptr, 4096, 1024, 1024);

  router_kernel<<<4096, 64, 0, stream>>>(x2, ln2s, ln2b, rw, ln2h, probs, topk, gates);

  assign_kernel<<<8, 256, 0, stream>>>(topk, counts, offsets, rows_tok, pair_pos);

  gemm_bt<64, 128, 1, true, true><<<dim3(2048 / 128, 8192 / 64, 8), 256, 0, stream>>>(
      ln2h, w1_t, b1, nullptr, h_buf, nullptr, rows_tok, counts, offsets, 8192, 2048, 1024);

  gemm_bt<64, 128, 0, false, true><<<dim3(1024 / 128, 8192 / 64, 8), 256, 0, stream>>>(
      h_buf, w2_t, b2, nullptr, eo, nullptr, nullptr, counts, offsets, 8192, 1024, 2048);

  combine_kernel<<<4097, 256, 0, stream>>>(x2, eo, gates, pair_pos, probs, topk,
                                           (float*)d_out, (float*)d_out + 4194304);
}